// Round 18
// baseline (125.955 us; speedup 1.0000x reference)
//
#include <hip/hip_runtime.h>
#include <hip/hip_bf16.h>

#define S_TOK 3072   // 64*48
#define NHEADS 8
#define KVT 12800    // u16 per KV tile: K 6144 ([96][64] swz) + V 6656 ([64][104])

typedef __attribute__((ext_vector_type(8))) short short8;
typedef __attribute__((ext_vector_type(4))) float floatx4;
typedef __attribute__((ext_vector_type(4))) unsigned short ushortx4;

__device__ __forceinline__ unsigned short f2bf(float f) {
  union { float f; unsigned u; } v; v.f = f;
  unsigned r = v.u + 0x7fffu + ((v.u >> 16) & 1u);   // RTN-even
  return (unsigned short)(r >> 16);
}
__device__ __forceinline__ float bf2f(unsigned short h) {
  union { unsigned u; float f; } v; v.u = (unsigned)h << 16;
  return v.f;
}
__device__ __forceinline__ unsigned pack2bf(float a, float b) {
  __hip_bfloat162 h = __float22bfloat162_rn(make_float2(a, b));
  union { __hip_bfloat162 h; unsigned u; } c; c.h = h;
  return c.u;
}
__device__ __forceinline__ void gload16(const void* g, void* l) {
  __builtin_amdgcn_global_load_lds(
      (const __attribute__((address_space(1))) unsigned int*)g,
      (__attribute__((address_space(3))) unsigned int*)l, 16, 0, 0);
}

// ---- merged converter: X hi/lo (blocks 0..1535), w_qkv^T (1536..1727),
// w_out^T (1728..1791); all outputs pre-swizzled for gload_lds staging ----
__global__ __launch_bounds__(256) void ga_conv_all(
    const float* __restrict__ X, const float* __restrict__ Wq,
    const float* __restrict__ Wo, unsigned short* __restrict__ xh,
    unsigned short* __restrict__ xl, unsigned short* __restrict__ wqh,
    unsigned short* __restrict__ wql, unsigned short* __restrict__ woh,
    unsigned short* __restrict__ wol) {
  const int blk = blockIdx.x;
  const int t = threadIdx.x;
  if (blk < 1536) {
    const int c = blk * 256 + t;
    const int m = c >> 6;
    const int c8 = (c & 63) << 3;
    const float* src = X + (size_t)m * 512 + c8;
    float4 v0 = *(const float4*)src, v1 = *(const float4*)(src + 4);
    float vv[8] = {v0.x, v0.y, v0.z, v0.w, v1.x, v1.y, v1.z, v1.w};
    union { unsigned short s[8]; short8 v; } hh, ll;
#pragma unroll
    for (int e = 0; e < 8; ++e) {
      hh.s[e] = f2bf(vv[e]);
      ll.s[e] = f2bf(vv[e] - bf2f(hh.s[e]));
    }
    const size_t dst = (size_t)m * 512 + (c8 ^ ((m & 7) << 3));
    *(short8*)&xh[dst] = hh.v;
    *(short8*)&xl[dst] = ll.v;
    return;
  }
  const int wq = (blk < 1728);
  const int b2 = wq ? (blk - 1536) : (blk - 1728);
  const int N = wq ? 1536 : 512;
  const float* W = wq ? Wq : Wo;
  unsigned short* th = wq ? wqh : woh;
  unsigned short* tl = wq ? wql : wol;
  const int k0 = (b2 & 7) * 64, n0 = (b2 >> 3) * 64;
  __shared__ float Ts[64][65];
#pragma unroll
  for (int i = 0; i < 4; ++i) {
    const int r = (t >> 4) + i * 16, c4 = (t & 15) * 4;
    float4 v = *(const float4*)&W[(size_t)(k0 + r) * N + n0 + c4];
    Ts[r][c4] = v.x; Ts[r][c4 + 1] = v.y; Ts[r][c4 + 2] = v.z; Ts[r][c4 + 3] = v.w;
  }
  __syncthreads();
#pragma unroll
  for (int j = 0; j < 2; ++j) {
    const int chunk = t * 2 + j;
    const int nl = chunk >> 3, m8 = chunk & 7;
    const int n = n0 + nl;
    const int ks = (m8 * 8) ^ ((n & 7) << 3);
    union { unsigned short s[8]; short8 v; } hh, ll;
#pragma unroll
    for (int e = 0; e < 8; ++e) {
      float f = Ts[ks + e][nl];
      hh.s[e] = f2bf(f);
      ll.s[e] = f2bf(f - bf2f(hh.s[e]));
    }
    const size_t dst = (size_t)n * 512 + k0 + m8 * 8;
    *(short8*)&th[dst] = hh.v;
    *(short8*)&tl[dst] = ll.v;
  }
}

// ---- bf16x3 MFMA GEMM for QKV; K AND V go directly into tiled KV buffer.
// V epilogue fuses the transpose+key-permute. Q/K 2 terms; V 3 terms.
template <int BM, int BN>
__global__ __launch_bounds__(256, 2) void ga_mm3(
    const unsigned short* __restrict__ Ah, const unsigned short* __restrict__ Al,
    const unsigned short* __restrict__ Bh, const unsigned short* __restrict__ Bl,
    unsigned short* __restrict__ Qd, unsigned short* __restrict__ KV) {
  const int tid = threadIdx.x;
  const int w = tid >> 6, l = tid & 63;
  const int g = l >> 4, ln = l & 15;
  const int wm = w >> 1, wn = w & 1;
  const int wgid = blockIdx.x;
  const int jj = (wgid & 7) * 72 + (wgid >> 3);
  const int m0 = (jj % 48) * BM;
  const int n0 = (jj / 48) * BN;
  const bool full3 = (n0 >= 1024);   // V blocks only
  constexpr int MI = BM / 32;
  constexpr int NI = BN / 32;
  __shared__ unsigned short Alds[2][BM * 64];
  __shared__ unsigned short Blds[2][BN * 64];
  floatx4 acc[MI][NI];
#pragma unroll
  for (int mi = 0; mi < MI; ++mi)
#pragma unroll
    for (int ni = 0; ni < NI; ++ni)
#pragma unroll
      for (int r = 0; r < 4; ++r) acc[mi][ni][r] = 0.f;

  for (int k0 = 0; k0 < 512; k0 += 64) {
    __syncthreads();
    {
      constexpr int PWA = (BM * 128) / 4096;
      constexpr int PWB = (BN * 128) / 4096;
      const char* ga_h = (const char*)(Ah + (size_t)m0 * 512 + k0);
      const char* ga_l = (const char*)(Al + (size_t)m0 * 512 + k0);
      const char* gb_h = (const char*)(Bh + (size_t)n0 * 512 + k0);
      const char* gb_l = (const char*)(Bl + (size_t)n0 * 512 + k0);
#pragma unroll
      for (int i = 0; i < PWA; ++i) {
        const int off = (w * PWA + i) * 1024;
        const int gb = ((off >> 7) + (l >> 3)) * 1024 + (l & 7) * 16;
        gload16(ga_h + gb, (char*)&Alds[0][0] + off);
        gload16(ga_l + gb, (char*)&Alds[1][0] + off);
      }
#pragma unroll
      for (int i = 0; i < PWB; ++i) {
        const int off = (w * PWB + i) * 1024;
        const int gb = ((off >> 7) + (l >> 3)) * 1024 + (l & 7) * 16;
        gload16(gb_h + gb, (char*)&Blds[0][0] + off);
        gload16(gb_l + gb, (char*)&Blds[1][0] + off);
      }
    }
    asm volatile("s_waitcnt vmcnt(0)" ::: "memory");
    __syncthreads();
#pragma unroll
    for (int kk = 0; kk < 64; kk += 32) {
      const int kbase = kk + g * 8;
      short8 ah[MI], al[MI], bh[NI], bl[NI];
#pragma unroll
      for (int mi = 0; mi < MI; ++mi) {
        const int row = wm * (BM / 2) + mi * 16 + ln;
        const int a = row * 64 + (kbase ^ ((row & 7) << 3));
        ah[mi] = *(const short8*)&Alds[0][a];
        al[mi] = *(const short8*)&Alds[1][a];
      }
#pragma unroll
      for (int ni = 0; ni < NI; ++ni) {
        const int row = wn * (BN / 2) + ni * 16 + ln;
        const int a = row * 64 + (kbase ^ ((row & 7) << 3));
        bh[ni] = *(const short8*)&Blds[0][a];
        bl[ni] = *(const short8*)&Blds[1][a];
      }
#pragma unroll
      for (int mi = 0; mi < MI; ++mi)
#pragma unroll
        for (int ni = 0; ni < NI; ++ni) {
          acc[mi][ni] = __builtin_amdgcn_mfma_f32_16x16x32_bf16(
              ah[mi], bh[ni], acc[mi][ni], 0, 0, 0);
          acc[mi][ni] = __builtin_amdgcn_mfma_f32_16x16x32_bf16(
              al[mi], bh[ni], acc[mi][ni], 0, 0, 0);
          if (full3)
            acc[mi][ni] = __builtin_amdgcn_mfma_f32_16x16x32_bf16(
                ah[mi], bl[ni], acc[mi][ni], 0, 0, 0);
        }
    }
  }
  // QKV scatter epilogue
  const int b = m0 / S_TOK;
  const int s_base = (m0 % S_TOK) + wm * (BM / 2);
#pragma unroll
  for (int ni = 0; ni < NI; ++ni) {
    const int ng = n0 + wn * (BN / 2) + ni * 16;
    const int which = ng >> 9;
    const int h = (ng >> 6) & 7;
    const int d = (ng & 63) + ln;
    const int bh = b * 8 + h;
    if (which == 1) {            // K: swizzled rows into KV K-region
      unsigned short* kp = KV + (size_t)bh * 32 * KVT;
#pragma unroll
      for (int mi = 0; mi < MI; ++mi)
#pragma unroll
        for (int r = 0; r < 4; ++r) {
          const int s = s_base + mi * 16 + g * 4 + r;
          const int tile = s / 96;
          const int r96 = s - tile * 96;
          kp[tile * KVT + r96 * 64 + (d ^ ((s & 7) << 3))] =
              f2bf(acc[mi][ni][r]);
        }
    } else if (which == 2) {     // V: transposed + key-permuted into KV V-region
      unsigned short* vt = KV + (size_t)bh * 32 * KVT + 6144;
#pragma unroll
      for (int mi = 0; mi < MI; ++mi) {
        const int s0 = s_base + mi * 16 + g * 4;   // 4 consecutive keys
        const int tile = s0 / 96;
        const int k96 = s0 - tile * 96;
        const int pb = (k96 >> 5) * 32 + ((k96 >> 2) & 3) * 8 + ((k96 >> 4) & 1) * 4;
        ushortx4 o = {f2bf(acc[mi][ni][0]), f2bf(acc[mi][ni][1]),
                      f2bf(acc[mi][ni][2]), f2bf(acc[mi][ni][3])};
        *(ushortx4*)&vt[(size_t)tile * KVT + d * 104 + pb] = o;
      }
    } else {                     // Q: pre-scaled row-major
      unsigned short* hp = Qd + (size_t)bh * S_TOK * 64;
#pragma unroll
      for (int mi = 0; mi < MI; ++mi)
#pragma unroll
        for (int r = 0; r < 4; ++r) {
          const int s = s_base + mi * 16 + g * 4 + r;
          hp[(size_t)s * 64 + d] = f2bf(acc[mi][ni][r] * 0.18033688f);
        }
    }
  }
}

// -- Pass B: attention; 8-wave blocks (256 q), dbuf KV staging, bias-in-C,
// XCD-local grid, setprio. Opart bf16, l f32.
__global__ __launch_bounds__(512) void ga_attn16(
    const unsigned short* __restrict__ Q, const unsigned short* __restrict__ KVg,
    const float* __restrict__ rowtab, const float* __restrict__ coltab,
    unsigned short* __restrict__ Opart, float* __restrict__ Lpart, int nsplit) {
  const int tid = threadIdx.x;
  const int w = tid >> 6;        // wave 0..7
  const int l = tid & 63;
  const int g = l >> 4;
  const int ln = l & 15;
  // XCD-aware decode: all blocks of one bh land on one XCD
  const int wgid = blockIdx.x;
  const int idx = wgid >> 3;
  const int bpb = 12 * nsplit;                  // blocks per bh
  const int bh = ((wgid & 7) << 1) + idx / bpb;
  const int rem = idx % bpb;
  const int sp = rem / 12;
  const int qb = rem % 12;
  const int h = bh & 7;
  const int q0 = qb * 256 + w * 32;
  const int tiles_per_split = 32 / nsplit;

  __shared__ float rtab[127];
  __shared__ float ctab[95];
  __shared__ unsigned short KVlds[2][KVT];   // 2 x 25600 B
  for (int i = tid; i < 127; i += 512) rtab[i] = rowtab[i * 8 + h] * 1.44269504f;
  for (int i = tid; i < 95; i += 512) ctab[i] = coltab[i * 8 + h] * 1.44269504f;

  const unsigned short* Qp = Q + (size_t)bh * S_TOK * 64;
  const unsigned short* KVp = KVg + (size_t)bh * 32 * KVT;

  const int t0 = sp * tiles_per_split;
  const int tend = t0 + tiles_per_split;

  auto STAGE = [&](int b, int t) {
    const char* src = (const char*)(KVp + (size_t)t * KVT);
    char* dst = (char*)&KVlds[b][0];
#pragma unroll
    for (int i = 0; i < 3; ++i)
      gload16(src + i * 8192 + tid * 16, dst + i * 8192 + tid * 16);
    if (tid < 64) gload16(src + 24576 + tid * 16, dst + 24576 + tid * 16);
  };

  STAGE(0, t0);
  asm volatile("s_waitcnt vmcnt(0)" ::: "memory");
  __syncthreads();

  int qr[2], qc[2];
  short8 qf[2][2];
  float ctr[2][3][4];
#pragma unroll
  for (int u = 0; u < 2; ++u) {
    const int q = q0 + u * 16 + ln;
    qr[u] = q / 48;
    qc[u] = q - qr[u] * 48;
    qf[u][0] = *(const short8*)&Qp[(size_t)q * 64 + g * 8];
    qf[u][1] = *(const short8*)&Qp[(size_t)q * 64 + 32 + g * 8];
    const float* cb = &ctab[qc[u] - g * 4 + 47];
#pragma unroll
    for (int m = 0; m < 3; ++m)
#pragma unroll
      for (int r = 0; r < 4; ++r) ctr[u][m][r] = cb[-(16 * m + r)];
  }

  short8 ones;
  {
    union { unsigned short s[8]; short8 v; } on;
#pragma unroll
    for (int j = 0; j < 8; ++j) on.s[j] = 0x3F80;  // bf16 1.0
    ones = on.v;
  }

  floatx4 o_acc[2][4];
  floatx4 o5[2];
#pragma unroll
  for (int u = 0; u < 2; ++u) {
#pragma unroll
    for (int r = 0; r < 4; ++r) o5[u][r] = 0.f;
#pragma unroll
    for (int dt = 0; dt < 4; ++dt)
#pragma unroll
      for (int r = 0; r < 4; ++r) o_acc[u][dt][r] = 0.f;
  }

  int cur = 0;
  for (int t = t0; t < tend; ++t) {
    if (t + 1 < tend) STAGE(cur ^ 1, t + 1);   // loads fly under compute
    const unsigned short* kb = &KVlds[cur][0];
    const unsigned short* vb = &KVlds[cur][6144];
    float rt[2][2];
#pragma unroll
    for (int u = 0; u < 2; ++u) {
      rt[u][0] = rtab[qr[u] + 63 - 2 * t] - 12.0f;
      rt[u][1] = rtab[qr[u] + 62 - 2 * t] - 12.0f;
    }
    const int swz = (ln & 7) << 3;
#pragma unroll
    for (int kc32 = 0; kc32 < 3; ++kc32) {
      float e[2][2][4];
#pragma unroll
      for (int kh = 0; kh < 2; ++kh) {
        const int kt = kc32 * 2 + kh;
        const int rb = (kt * 16 + ln) * 64;
        short8 kf0 = *(const short8*)&kb[rb + ((g * 8) ^ swz)];
        short8 kf1 = *(const short8*)&kb[rb + ((32 + g * 8) ^ swz)];
        const int m = kt % 3, wrap = kt / 3;
#pragma unroll
        for (int u = 0; u < 2; ++u) {
          // bias folded into the MFMA C-operand: D = K·Q^T + bias
          floatx4 s;
#pragma unroll
          for (int r = 0; r < 4; ++r) s[r] = rt[u][wrap] + ctr[u][m][r];
          s = __builtin_amdgcn_mfma_f32_16x16x32_bf16(kf0, qf[u][0], s, 0, 0, 0);
          s = __builtin_amdgcn_mfma_f32_16x16x32_bf16(kf1, qf[u][1], s, 0, 0, 0);
#pragma unroll
          for (int r = 0; r < 4; ++r)
            e[u][kh][r] = __builtin_amdgcn_exp2f(s[r]);
        }
      }
      short8 pf[2];
#pragma unroll
      for (int u = 0; u < 2; ++u) {
        union { unsigned uu[4]; short8 v; } pk;
        pk.uu[0] = pack2bf(e[u][0][0], e[u][0][1]);
        pk.uu[1] = pack2bf(e[u][0][2], e[u][0][3]);
        pk.uu[2] = pack2bf(e[u][1][0], e[u][1][1]);
        pk.uu[3] = pack2bf(e[u][1][2], e[u][1][3]);
        pf[u] = pk.v;
      }
      __builtin_amdgcn_s_setprio(1);   // favor the MFMA-feeding wave (T5)
#pragma unroll
      for (int dt = 0; dt < 4; ++dt) {
        const int vrow = dt * 16 + ln;
        short8 vf = *(const short8*)&vb[vrow * 104 + kc32 * 32 + g * 8];
        o_acc[0][dt] =
            __builtin_amdgcn_mfma_f32_16x16x32_bf16(pf[0], vf, o_acc[0][dt], 0, 0, 0);
        o_acc[1][dt] =
            __builtin_amdgcn_mfma_f32_16x16x32_bf16(pf[1], vf, o_acc[1][dt], 0, 0, 0);
      }
      o5[0] = __builtin_amdgcn_mfma_f32_16x16x32_bf16(pf[0], ones, o5[0], 0, 0, 0);
      o5[1] = __builtin_amdgcn_mfma_f32_16x16x32_bf16(pf[1], ones, o5[1], 0, 0, 0);
      __builtin_amdgcn_s_setprio(0);
    }
    asm volatile("s_waitcnt vmcnt(0)" ::: "memory");  // my stage loads landed
    __syncthreads();            // everyone's landed; everyone done reading cur
    cur ^= 1;
  }
  const size_t rowbase = (size_t)(sp * 16 + bh) * S_TOK;
#pragma unroll
  for (int u = 0; u < 2; ++u) {
    if (ln == 0) {
#pragma unroll
      for (int r = 0; r < 4; ++r)
        Lpart[rowbase + q0 + u * 16 + g * 4 + r] = o5[u][r];
    }
#pragma unroll
    for (int dt = 0; dt < 4; ++dt)
#pragma unroll
      for (int r = 0; r < 4; ++r)
        Opart[(rowbase + q0 + u * 16 + g * 4 + r) * 64 + dt * 16 + ln] =
            f2bf(o_acc[u][dt][r]);
  }
}

// --- Pass C: output GEMM (bf16) + fused split-K combine; XCD m-chunk grid ---
template <int NS>
__global__ __launch_bounds__(256, 2) void ga_outmm(
    const unsigned short* __restrict__ Opart, const float* __restrict__ Lpart,
    const unsigned short* __restrict__ Bh_, float* __restrict__ Out) {
  const int tid = threadIdx.x;
  const int w = tid >> 6, l = tid & 63;
  const int g = l >> 4, ln = l & 15;
  const int wm = w >> 1, wn = w & 1;
  const int wgid = blockIdx.x;
  const int i = wgid >> 3;
  const int m0 = ((wgid & 7) * 12 + (i >> 3)) * 64;
  const int n0 = (i & 7) * 64;
  __shared__ unsigned short Alds[64 * 64];
  __shared__ unsigned short Blds[2][64 * 64];
  floatx4 acc[2][2];
#pragma unroll
  for (int mi = 0; mi < 2; ++mi)
#pragma unroll
    for (int ni = 0; ni < 2; ++ni)
#pragma unroll
      for (int r = 0; r < 4; ++r) acc[mi][ni][r] = 0.f;

  const int lm = tid >> 2, lk4 = tid & 3;
  const int m = m0 + lm;
  const int b = (m >= S_TOK) ? 1 : 0;
  const int q = m - b * S_TOK;

  float v[16];
  float ls;
  auto ALOAD = [&](int h) {
    const int bh = b * 8 + h;
    ls = 0.f;
#pragma unroll
    for (int s = 0; s < NS; ++s) {
      const size_t row = (size_t)(s * 16 + bh) * S_TOK + q;
      ls += Lpart[row];
      const unsigned short* op = &Opart[row * 64 + lk4 * 16];
      short8 a0 = *(const short8*)op;
      short8 a1 = *(const short8*)(op + 8);
#pragma unroll
      for (int j = 0; j < 8; ++j) {
        float f0 = bf2f((unsigned short)a0[j]);
        float f1 = bf2f((unsigned short)a1[j]);
        if (s == 0) {
          v[j] = f0;
          v[8 + j] = f1;
        } else {
          v[j] += f0;
          v[8 + j] += f1;
        }
      }
    }
  };
  auto BISSUE = [&](int h, int buf) {
    const char* gb = (const char*)(Bh_ + (size_t)n0 * 512 + h * 64);
#pragma unroll
    for (int i2 = 0; i2 < 2; ++i2) {
      const int off = (w * 2 + i2) * 1024;
      const int gbo = ((off >> 7) + (l >> 3)) * 1024 + (l & 7) * 16;
      gload16(gb + gbo, (char*)&Blds[buf][0] + off);
    }
  };
  auto AWRITE = [&]() {
    const float inv = 1.0f / ls;
    unsigned pk[8];
#pragma unroll
    for (int j = 0; j < 8; ++j)
      pk[j] = pack2bf(v[2 * j] * inv, v[2 * j + 1] * inv);
    const int sw = (lm & 7) << 3;
    unsigned short* ab = &Alds[lm * 64];
#pragma unroll
    for (int j = 0; j < 4; ++j)
      *(uint2*)&ab[(lk4 * 16 + j * 4) ^ sw] = make_uint2(pk[2 * j], pk[2 * j + 1]);
  };

  // prologue: A(0), B(0)
  ALOAD(0);
  BISSUE(0, 0);
  AWRITE();                                          // waits on v automatically
  asm volatile("s_waitcnt vmcnt(0)" ::: "memory");   // B(0) landed
  __syncthreads();                                   // Alds(0)+Blds[0] visible

  int cur = 0;
  for (int h = 0; h < 8; ++h) {
    if (h < 7) {               // next panel's loads fly under this compute
      ALOAD(h + 1);
      BISSUE(h + 1, cur ^ 1);
    }
#pragma unroll
    for (int kk = 0; kk < 64; kk += 32) {
      const int kbase = kk + g * 8;
      short8 af[2], bf[2];
#pragma unroll
      for (int mi = 0; mi < 2; ++mi) {
        const int row = wm * 32 + mi * 16 + ln;
        af[mi] = *(const short8*)&Alds[row * 64 + (kbase ^ ((row & 7) << 3))];
      }
#pragma unroll
      for (int ni = 0; ni < 2; ++ni) {
        const int row = wn * 32 + ni * 16 + ln;
        bf[ni] =
            *(const short8*)&Blds[cur][row * 64 + (kbase ^ ((row & 7) << 3))];
      }
#pragma unroll
      for (int mi = 0; mi < 2; ++mi)
#pragma unroll
        for (int ni = 0; ni < 2; ++ni)
          acc[mi][ni] = __builtin_amdgcn_mfma_f32_16x16x32_bf16(
              af[mi], bf[ni], acc[mi][ni], 0, 0, 0);
    }
    if (h < 7) {
      __syncthreads();   // all waves done reading Alds; B(h+1) long since landed
      AWRITE();          // stage A(h+1) into Alds
      __syncthreads();   // Alds(h+1) visible
      cur ^= 1;
    }
  }
#pragma unroll
  for (int mi = 0; mi < 2; ++mi)
#pragma unroll
    for (int ni = 0; ni < 2; ++ni)
#pragma unroll
      for (int r = 0; r < 4; ++r)
        Out[(size_t)(m0 + wm * 32 + mi * 16 + g * 4 + r) * 512 + n0 +
            wn * 32 + ni * 16 + ln] = acc[mi][ni][r];
}

extern "C" void kernel_launch(void* const* d_in, const int* in_sizes, int n_in,
                              void* d_out, int out_size, void* d_ws,
                              size_t ws_size, hipStream_t stream) {
  const float* x = (const float*)d_in[0];       // [2,64,48,512]
  const float* w_qkv = (const float*)d_in[1];   // [512,1536]
  const float* w_out = (const float*)d_in[2];   // [512,512]
  const float* rrow = (const float*)d_in[3];    // [127,8]
  const float* rcol = (const float*)d_in[4];    // [95,8]
  float* out = (float*)d_out;                   // [6144,512]

  unsigned short* ws16 = (unsigned short*)d_ws;
  unsigned short* xh = ws16;                    // 3145728
  unsigned short* xl = xh + 3145728;            // 3145728
  unsigned short* wqh = xl + 3145728;           // 786432
  unsigned short* wql = wqh + 786432;
  unsigned short* woh = wql + 786432;           // 262144
  unsigned short* wol = woh + 262144;
  unsigned short* Qb = wol + 262144;            // 3145728
  unsigned short* KV = Qb + 3145728;            // 16*32*12800 = 6553600
  unsigned short* Opart = KV + 6553600;         // bf16
  const size_t base_bytes =
      ((size_t)3145728 * 3 + 786432 * 2 + 262144 * 2 + 6553600) * 2;
  const size_t per_split = (size_t)3145728 * 2 + (size_t)49152 * 4;
  const int nsplit = (ws_size >= base_bytes + 4 * per_split) ? 4
                   : (ws_size >= base_bytes + 2 * per_split) ? 2 : 1;
  float* Lpart = (float*)(Opart + (size_t)nsplit * 3145728);

  ga_conv_all<<<1792, 256, 0, stream>>>(x, w_qkv, w_out, xh, xl, wqh, wql, woh,
                                        wol);
  ga_mm3<128, 128><<<576, 256, 0, stream>>>(xh, xl, wqh, wql, Qb, KV);
  ga_attn16<<<12 * 16 * nsplit, 512, 0, stream>>>(
      Qb, KV, rrow, rcol, Opart, Lpart, nsplit);
  if (nsplit == 4)
    ga_outmm<4><<<768, 256, 0, stream>>>(Opart, Lpart, woh, out);
  else if (nsplit == 2)
    ga_outmm<2><<<768, 256, 0, stream>>>(Opart, Lpart, woh, out);
  else
    ga_outmm<1><<<768, 256, 0, stream>>>(Opart, Lpart, woh, out);
}

// Round 19
// 115.195 us; speedup vs baseline: 1.0934x; 1.0934x over previous
//
#include <hip/hip_runtime.h>
#include <hip/hip_bf16.h>

#define S_TOK 3072   // 64*48
#define NHEADS 8
#define KVT 12800    // u16 per KV tile: K 6144 ([96][64] swz) + V 6656 ([64][104])

typedef __attribute__((ext_vector_type(8))) short short8;
typedef __attribute__((ext_vector_type(4))) float floatx4;
typedef __attribute__((ext_vector_type(4))) unsigned short ushortx4;

__device__ __forceinline__ unsigned short f2bf(float f) {
  union { float f; unsigned u; } v; v.f = f;
  unsigned r = v.u + 0x7fffu + ((v.u >> 16) & 1u);   // RTN-even
  return (unsigned short)(r >> 16);
}
__device__ __forceinline__ float bf2f(unsigned short h) {
  union { unsigned u; float f; } v; v.u = (unsigned)h << 16;
  return v.f;
}
__device__ __forceinline__ unsigned pack2bf(float a, float b) {
  __hip_bfloat162 h = __float22bfloat162_rn(make_float2(a, b));
  union { __hip_bfloat162 h; unsigned u; } c; c.h = h;
  return c.u;
}
__device__ __forceinline__ void gload16(const void* g, void* l) {
  __builtin_amdgcn_global_load_lds(
      (const __attribute__((address_space(1))) unsigned int*)g,
      (__attribute__((address_space(3))) unsigned int*)l, 16, 0, 0);
}

// ---- merged converter: X hi/lo (blocks 0..1535), w_qkv^T (1536..1727),
// w_out^T (1728..1791); all outputs pre-swizzled for gload_lds staging ----
__global__ __launch_bounds__(256) void ga_conv_all(
    const float* __restrict__ X, const float* __restrict__ Wq,
    const float* __restrict__ Wo, unsigned short* __restrict__ xh,
    unsigned short* __restrict__ xl, unsigned short* __restrict__ wqh,
    unsigned short* __restrict__ wql, unsigned short* __restrict__ woh,
    unsigned short* __restrict__ wol) {
  const int blk = blockIdx.x;
  const int t = threadIdx.x;
  if (blk < 1536) {
    const int c = blk * 256 + t;
    const int m = c >> 6;
    const int c8 = (c & 63) << 3;
    const float* src = X + (size_t)m * 512 + c8;
    float4 v0 = *(const float4*)src, v1 = *(const float4*)(src + 4);
    float vv[8] = {v0.x, v0.y, v0.z, v0.w, v1.x, v1.y, v1.z, v1.w};
    union { unsigned short s[8]; short8 v; } hh, ll;
#pragma unroll
    for (int e = 0; e < 8; ++e) {
      hh.s[e] = f2bf(vv[e]);
      ll.s[e] = f2bf(vv[e] - bf2f(hh.s[e]));
    }
    const size_t dst = (size_t)m * 512 + (c8 ^ ((m & 7) << 3));
    *(short8*)&xh[dst] = hh.v;
    *(short8*)&xl[dst] = ll.v;
    return;
  }
  const int wq = (blk < 1728);
  const int b2 = wq ? (blk - 1536) : (blk - 1728);
  const int N = wq ? 1536 : 512;
  const float* W = wq ? Wq : Wo;
  unsigned short* th = wq ? wqh : woh;
  unsigned short* tl = wq ? wql : wol;
  const int k0 = (b2 & 7) * 64, n0 = (b2 >> 3) * 64;
  __shared__ float Ts[64][65];
#pragma unroll
  for (int i = 0; i < 4; ++i) {
    const int r = (t >> 4) + i * 16, c4 = (t & 15) * 4;
    float4 v = *(const float4*)&W[(size_t)(k0 + r) * N + n0 + c4];
    Ts[r][c4] = v.x; Ts[r][c4 + 1] = v.y; Ts[r][c4 + 2] = v.z; Ts[r][c4 + 3] = v.w;
  }
  __syncthreads();
#pragma unroll
  for (int j = 0; j < 2; ++j) {
    const int chunk = t * 2 + j;
    const int nl = chunk >> 3, m8 = chunk & 7;
    const int n = n0 + nl;
    const int ks = (m8 * 8) ^ ((n & 7) << 3);
    union { unsigned short s[8]; short8 v; } hh, ll;
#pragma unroll
    for (int e = 0; e < 8; ++e) {
      float f = Ts[ks + e][nl];
      hh.s[e] = f2bf(f);
      ll.s[e] = f2bf(f - bf2f(hh.s[e]));
    }
    const size_t dst = (size_t)n * 512 + k0 + m8 * 8;
    *(short8*)&th[dst] = hh.v;
    *(short8*)&tl[dst] = ll.v;
  }
}

// ---- bf16x3 MFMA GEMM for QKV; K AND V go directly into tiled KV buffer.
// V epilogue fuses the transpose+key-permute. Q/K 2 terms; V 3 terms.
template <int BM, int BN>
__global__ __launch_bounds__(256, 2) void ga_mm3(
    const unsigned short* __restrict__ Ah, const unsigned short* __restrict__ Al,
    const unsigned short* __restrict__ Bh, const unsigned short* __restrict__ Bl,
    unsigned short* __restrict__ Qd, unsigned short* __restrict__ KV) {
  const int tid = threadIdx.x;
  const int w = tid >> 6, l = tid & 63;
  const int g = l >> 4, ln = l & 15;
  const int wm = w >> 1, wn = w & 1;
  const int wgid = blockIdx.x;
  const int jj = (wgid & 7) * 72 + (wgid >> 3);
  const int m0 = (jj % 48) * BM;
  const int n0 = (jj / 48) * BN;
  const bool full3 = (n0 >= 1024);   // V blocks only
  constexpr int MI = BM / 32;
  constexpr int NI = BN / 32;
  __shared__ unsigned short Alds[2][BM * 64];
  __shared__ unsigned short Blds[2][BN * 64];
  floatx4 acc[MI][NI];
#pragma unroll
  for (int mi = 0; mi < MI; ++mi)
#pragma unroll
    for (int ni = 0; ni < NI; ++ni)
#pragma unroll
      for (int r = 0; r < 4; ++r) acc[mi][ni][r] = 0.f;

  for (int k0 = 0; k0 < 512; k0 += 64) {
    __syncthreads();
    {
      constexpr int PWA = (BM * 128) / 4096;
      constexpr int PWB = (BN * 128) / 4096;
      const char* ga_h = (const char*)(Ah + (size_t)m0 * 512 + k0);
      const char* ga_l = (const char*)(Al + (size_t)m0 * 512 + k0);
      const char* gb_h = (const char*)(Bh + (size_t)n0 * 512 + k0);
      const char* gb_l = (const char*)(Bl + (size_t)n0 * 512 + k0);
#pragma unroll
      for (int i = 0; i < PWA; ++i) {
        const int off = (w * PWA + i) * 1024;
        const int gb = ((off >> 7) + (l >> 3)) * 1024 + (l & 7) * 16;
        gload16(ga_h + gb, (char*)&Alds[0][0] + off);
        gload16(ga_l + gb, (char*)&Alds[1][0] + off);
      }
#pragma unroll
      for (int i = 0; i < PWB; ++i) {
        const int off = (w * PWB + i) * 1024;
        const int gb = ((off >> 7) + (l >> 3)) * 1024 + (l & 7) * 16;
        gload16(gb_h + gb, (char*)&Blds[0][0] + off);
        gload16(gb_l + gb, (char*)&Blds[1][0] + off);
      }
    }
    asm volatile("s_waitcnt vmcnt(0)" ::: "memory");
    __syncthreads();
#pragma unroll
    for (int kk = 0; kk < 64; kk += 32) {
      const int kbase = kk + g * 8;
      short8 ah[MI], al[MI], bh[NI], bl[NI];
#pragma unroll
      for (int mi = 0; mi < MI; ++mi) {
        const int row = wm * (BM / 2) + mi * 16 + ln;
        const int a = row * 64 + (kbase ^ ((row & 7) << 3));
        ah[mi] = *(const short8*)&Alds[0][a];
        al[mi] = *(const short8*)&Alds[1][a];
      }
#pragma unroll
      for (int ni = 0; ni < NI; ++ni) {
        const int row = wn * (BN / 2) + ni * 16 + ln;
        const int a = row * 64 + (kbase ^ ((row & 7) << 3));
        bh[ni] = *(const short8*)&Blds[0][a];
        bl[ni] = *(const short8*)&Blds[1][a];
      }
#pragma unroll
      for (int mi = 0; mi < MI; ++mi)
#pragma unroll
        for (int ni = 0; ni < NI; ++ni) {
          acc[mi][ni] = __builtin_amdgcn_mfma_f32_16x16x32_bf16(
              ah[mi], bh[ni], acc[mi][ni], 0, 0, 0);
          acc[mi][ni] = __builtin_amdgcn_mfma_f32_16x16x32_bf16(
              al[mi], bh[ni], acc[mi][ni], 0, 0, 0);
          if (full3)
            acc[mi][ni] = __builtin_amdgcn_mfma_f32_16x16x32_bf16(
                ah[mi], bl[ni], acc[mi][ni], 0, 0, 0);
        }
    }
  }
  // QKV scatter epilogue
  const int b = m0 / S_TOK;
  const int s_base = (m0 % S_TOK) + wm * (BM / 2);
#pragma unroll
  for (int ni = 0; ni < NI; ++ni) {
    const int ng = n0 + wn * (BN / 2) + ni * 16;
    const int which = ng >> 9;
    const int h = (ng >> 6) & 7;
    const int d = (ng & 63) + ln;
    const int bh = b * 8 + h;
    if (which == 1) {            // K: swizzled rows into KV K-region
      unsigned short* kp = KV + (size_t)bh * 32 * KVT;
#pragma unroll
      for (int mi = 0; mi < MI; ++mi)
#pragma unroll
        for (int r = 0; r < 4; ++r) {
          const int s = s_base + mi * 16 + g * 4 + r;
          const int tile = s / 96;
          const int r96 = s - tile * 96;
          kp[tile * KVT + r96 * 64 + (d ^ ((s & 7) << 3))] =
              f2bf(acc[mi][ni][r]);
        }
    } else if (which == 2) {     // V: transposed + key-permuted into KV V-region
      unsigned short* vt = KV + (size_t)bh * 32 * KVT + 6144;
#pragma unroll
      for (int mi = 0; mi < MI; ++mi) {
        const int s0 = s_base + mi * 16 + g * 4;   // 4 consecutive keys
        const int tile = s0 / 96;
        const int k96 = s0 - tile * 96;
        const int pb = (k96 >> 5) * 32 + ((k96 >> 2) & 3) * 8 + ((k96 >> 4) & 1) * 4;
        ushortx4 o = {f2bf(acc[mi][ni][0]), f2bf(acc[mi][ni][1]),
                      f2bf(acc[mi][ni][2]), f2bf(acc[mi][ni][3])};
        *(ushortx4*)&vt[(size_t)tile * KVT + d * 104 + pb] = o;
      }
    } else {                     // Q: pre-scaled row-major
      unsigned short* hp = Qd + (size_t)bh * S_TOK * 64;
#pragma unroll
      for (int mi = 0; mi < MI; ++mi)
#pragma unroll
        for (int r = 0; r < 4; ++r) {
          const int s = s_base + mi * 16 + g * 4 + r;
          hp[(size_t)s * 64 + d] = f2bf(acc[mi][ni][r] * 0.18033688f);
        }
    }
  }
}

// -- Pass B: attention; dbuf KV staging, bias-in-C, XCD-local grid, setprio --
// Opart written as bf16 (l stays f32). 4-wave blocks (R17 config).
__global__ __launch_bounds__(256) void ga_attn16(
    const unsigned short* __restrict__ Q, const unsigned short* __restrict__ KVg,
    const float* __restrict__ rowtab, const float* __restrict__ coltab,
    unsigned short* __restrict__ Opart, float* __restrict__ Lpart, int nsplit) {
  const int tid = threadIdx.x;
  const int w = tid >> 6;
  const int l = tid & 63;
  const int g = l >> 4;
  const int ln = l & 15;
  // XCD-aware decode: all blocks of one bh land on one XCD
  const int wgid = blockIdx.x;
  const int idx = wgid >> 3;
  const int bpb = 24 * nsplit;                  // blocks per bh
  const int bh = ((wgid & 7) << 1) + idx / bpb;
  const int rem = idx % bpb;
  const int sp = rem / 24;
  const int qb = rem % 24;
  const int h = bh & 7;
  const int q0 = qb * 128 + w * 32;
  const int tiles_per_split = 32 / nsplit;

  __shared__ float rtab[127];
  __shared__ float ctab[95];
  __shared__ unsigned short KVlds[2][KVT];   // 2 x 25600 B
  for (int i = tid; i < 127; i += 256) rtab[i] = rowtab[i * 8 + h] * 1.44269504f;
  for (int i = tid; i < 95; i += 256) ctab[i] = coltab[i * 8 + h] * 1.44269504f;

  const unsigned short* Qp = Q + (size_t)bh * S_TOK * 64;
  const unsigned short* KVp = KVg + (size_t)bh * 32 * KVT;

  const int t0 = sp * tiles_per_split;
  const int tend = t0 + tiles_per_split;

  auto STAGE = [&](int b, int t) {
    const char* src = (const char*)(KVp + (size_t)t * KVT);
    char* dst = (char*)&KVlds[b][0];
#pragma unroll
    for (int i = 0; i < 6; ++i)
      gload16(src + i * 4096 + tid * 16, dst + i * 4096 + tid * 16);
    if (tid < 64) gload16(src + 24576 + tid * 16, dst + 24576 + tid * 16);
  };

  STAGE(0, t0);
  asm volatile("s_waitcnt vmcnt(0)" ::: "memory");
  __syncthreads();

  int qr[2], qc[2];
  short8 qf[2][2];
  float ctr[2][3][4];
#pragma unroll
  for (int u = 0; u < 2; ++u) {
    const int q = q0 + u * 16 + ln;
    qr[u] = q / 48;
    qc[u] = q - qr[u] * 48;
    qf[u][0] = *(const short8*)&Qp[(size_t)q * 64 + g * 8];
    qf[u][1] = *(const short8*)&Qp[(size_t)q * 64 + 32 + g * 8];
    const float* cb = &ctab[qc[u] - g * 4 + 47];
#pragma unroll
    for (int m = 0; m < 3; ++m)
#pragma unroll
      for (int r = 0; r < 4; ++r) ctr[u][m][r] = cb[-(16 * m + r)];
  }

  short8 ones;
  {
    union { unsigned short s[8]; short8 v; } on;
#pragma unroll
    for (int j = 0; j < 8; ++j) on.s[j] = 0x3F80;  // bf16 1.0
    ones = on.v;
  }

  floatx4 o_acc[2][4];
  floatx4 o5[2];
#pragma unroll
  for (int u = 0; u < 2; ++u) {
#pragma unroll
    for (int r = 0; r < 4; ++r) o5[u][r] = 0.f;
#pragma unroll
    for (int dt = 0; dt < 4; ++dt)
#pragma unroll
      for (int r = 0; r < 4; ++r) o_acc[u][dt][r] = 0.f;
  }

  int cur = 0;
  for (int t = t0; t < tend; ++t) {
    if (t + 1 < tend) STAGE(cur ^ 1, t + 1);   // loads fly under compute
    const unsigned short* kb = &KVlds[cur][0];
    const unsigned short* vb = &KVlds[cur][6144];
    float rt[2][2];
#pragma unroll
    for (int u = 0; u < 2; ++u) {
      rt[u][0] = rtab[qr[u] + 63 - 2 * t] - 12.0f;
      rt[u][1] = rtab[qr[u] + 62 - 2 * t] - 12.0f;
    }
    const int swz = (ln & 7) << 3;
#pragma unroll
    for (int kc32 = 0; kc32 < 3; ++kc32) {
      float e[2][2][4];
#pragma unroll
      for (int kh = 0; kh < 2; ++kh) {
        const int kt = kc32 * 2 + kh;
        const int rb = (kt * 16 + ln) * 64;
        short8 kf0 = *(const short8*)&kb[rb + ((g * 8) ^ swz)];
        short8 kf1 = *(const short8*)&kb[rb + ((32 + g * 8) ^ swz)];
        const int m = kt % 3, wrap = kt / 3;
#pragma unroll
        for (int u = 0; u < 2; ++u) {
          // bias folded into the MFMA C-operand: D = K·Q^T + bias
          floatx4 s;
#pragma unroll
          for (int r = 0; r < 4; ++r) s[r] = rt[u][wrap] + ctr[u][m][r];
          s = __builtin_amdgcn_mfma_f32_16x16x32_bf16(kf0, qf[u][0], s, 0, 0, 0);
          s = __builtin_amdgcn_mfma_f32_16x16x32_bf16(kf1, qf[u][1], s, 0, 0, 0);
#pragma unroll
          for (int r = 0; r < 4; ++r)
            e[u][kh][r] = __builtin_amdgcn_exp2f(s[r]);
        }
      }
      short8 pf[2];
#pragma unroll
      for (int u = 0; u < 2; ++u) {
        union { unsigned uu[4]; short8 v; } pk;
        pk.uu[0] = pack2bf(e[u][0][0], e[u][0][1]);
        pk.uu[1] = pack2bf(e[u][0][2], e[u][0][3]);
        pk.uu[2] = pack2bf(e[u][1][0], e[u][1][1]);
        pk.uu[3] = pack2bf(e[u][1][2], e[u][1][3]);
        pf[u] = pk.v;
      }
      __builtin_amdgcn_s_setprio(1);   // favor the MFMA-feeding wave (T5)
#pragma unroll
      for (int dt = 0; dt < 4; ++dt) {
        const int vrow = dt * 16 + ln;
        short8 vf = *(const short8*)&vb[vrow * 104 + kc32 * 32 + g * 8];
        o_acc[0][dt] =
            __builtin_amdgcn_mfma_f32_16x16x32_bf16(pf[0], vf, o_acc[0][dt], 0, 0, 0);
        o_acc[1][dt] =
            __builtin_amdgcn_mfma_f32_16x16x32_bf16(pf[1], vf, o_acc[1][dt], 0, 0, 0);
      }
      o5[0] = __builtin_amdgcn_mfma_f32_16x16x32_bf16(pf[0], ones, o5[0], 0, 0, 0);
      o5[1] = __builtin_amdgcn_mfma_f32_16x16x32_bf16(pf[1], ones, o5[1], 0, 0, 0);
      __builtin_amdgcn_s_setprio(0);
    }
    asm volatile("s_waitcnt vmcnt(0)" ::: "memory");  // my stage loads landed
    __syncthreads();            // everyone's landed; everyone done reading cur
    cur ^= 1;
  }
  const size_t rowbase = (size_t)(sp * 16 + bh) * S_TOK;
#pragma unroll
  for (int u = 0; u < 2; ++u) {
    if (ln == 0) {
#pragma unroll
      for (int r = 0; r < 4; ++r)
        Lpart[rowbase + q0 + u * 16 + g * 4 + r] = o5[u][r];
    }
#pragma unroll
    for (int dt = 0; dt < 4; ++dt)
#pragma unroll
      for (int r = 0; r < 4; ++r)
        Opart[(rowbase + q0 + u * 16 + g * 4 + r) * 64 + dt * 16 + ln] =
            f2bf(o_acc[u][dt][r]);
  }
}

// --- Pass C: output GEMM (bf16) + fused split-K combine; XCD m-chunk grid ---
template <int NS>
__global__ __launch_bounds__(256, 2) void ga_outmm(
    const unsigned short* __restrict__ Opart, const float* __restrict__ Lpart,
    const unsigned short* __restrict__ Bh_, float* __restrict__ Out) {
  const int tid = threadIdx.x;
  const int w = tid >> 6, l = tid & 63;
  const int g = l >> 4, ln = l & 15;
  const int wm = w >> 1, wn = w & 1;
  const int wgid = blockIdx.x;
  const int i = wgid >> 3;
  const int m0 = ((wgid & 7) * 12 + (i >> 3)) * 64;
  const int n0 = (i & 7) * 64;
  __shared__ unsigned short Alds[64 * 64];
  __shared__ unsigned short Blds[2][64 * 64];
  floatx4 acc[2][2];
#pragma unroll
  for (int mi = 0; mi < 2; ++mi)
#pragma unroll
    for (int ni = 0; ni < 2; ++ni)
#pragma unroll
      for (int r = 0; r < 4; ++r) acc[mi][ni][r] = 0.f;

  const int lm = tid >> 2, lk4 = tid & 3;
  const int m = m0 + lm;
  const int b = (m >= S_TOK) ? 1 : 0;
  const int q = m - b * S_TOK;

  float v[16];
  float ls;
  auto ALOAD = [&](int h) {
    const int bh = b * 8 + h;
    ls = 0.f;
#pragma unroll
    for (int s = 0; s < NS; ++s) {
      const size_t row = (size_t)(s * 16 + bh) * S_TOK + q;
      ls += Lpart[row];
      const unsigned short* op = &Opart[row * 64 + lk4 * 16];
      short8 a0 = *(const short8*)op;
      short8 a1 = *(const short8*)(op + 8);
#pragma unroll
      for (int j = 0; j < 8; ++j) {
        float f0 = bf2f((unsigned short)a0[j]);
        float f1 = bf2f((unsigned short)a1[j]);
        if (s == 0) {
          v[j] = f0;
          v[8 + j] = f1;
        } else {
          v[j] += f0;
          v[8 + j] += f1;
        }
      }
    }
  };
  auto BISSUE = [&](int h, int buf) {
    const char* gb = (const char*)(Bh_ + (size_t)n0 * 512 + h * 64);
#pragma unroll
    for (int i2 = 0; i2 < 2; ++i2) {
      const int off = (w * 2 + i2) * 1024;
      const int gbo = ((off >> 7) + (l >> 3)) * 1024 + (l & 7) * 16;
      gload16(gb + gbo, (char*)&Blds[buf][0] + off);
    }
  };
  auto AWRITE = [&]() {
    const float inv = 1.0f / ls;
    unsigned pk[8];
#pragma unroll
    for (int j = 0; j < 8; ++j)
      pk[j] = pack2bf(v[2 * j] * inv, v[2 * j + 1] * inv);
    const int sw = (lm & 7) << 3;
    unsigned short* ab = &Alds[lm * 64];
#pragma unroll
    for (int j = 0; j < 4; ++j)
      *(uint2*)&ab[(lk4 * 16 + j * 4) ^ sw] = make_uint2(pk[2 * j], pk[2 * j + 1]);
  };

  // prologue: A(0), B(0)
  ALOAD(0);
  BISSUE(0, 0);
  AWRITE();                                          // waits on v automatically
  asm volatile("s_waitcnt vmcnt(0)" ::: "memory");   // B(0) landed
  __syncthreads();                                   // Alds(0)+Blds[0] visible

  int cur = 0;
  for (int h = 0; h < 8; ++h) {
    if (h < 7) {               // next panel's loads fly under this compute
      ALOAD(h + 1);
      BISSUE(h + 1, cur ^ 1);
    }
#pragma unroll
    for (int kk = 0; kk < 64; kk += 32) {
      const int kbase = kk + g * 8;
      short8 af[2], bf[2];
#pragma unroll
      for (int mi = 0; mi < 2; ++mi) {
        const int row = wm * 32 + mi * 16 + ln;
        af[mi] = *(const short8*)&Alds[row * 64 + (kbase ^ ((row & 7) << 3))];
      }
#pragma unroll
      for (int ni = 0; ni < 2; ++ni) {
        const int row = wn * 32 + ni * 16 + ln;
        bf[ni] =
            *(const short8*)&Blds[cur][row * 64 + (kbase ^ ((row & 7) << 3))];
      }
#pragma unroll
      for (int mi = 0; mi < 2; ++mi)
#pragma unroll
        for (int ni = 0; ni < 2; ++ni)
          acc[mi][ni] = __builtin_amdgcn_mfma_f32_16x16x32_bf16(
              af[mi], bf[ni], acc[mi][ni], 0, 0, 0);
    }
    if (h < 7) {
      __syncthreads();   // all waves done reading Alds; B(h+1) long since landed
      AWRITE();          // stage A(h+1) into Alds
      __syncthreads();   // Alds(h+1) visible
      cur ^= 1;
    }
  }
#pragma unroll
  for (int mi = 0; mi < 2; ++mi)
#pragma unroll
    for (int ni = 0; ni < 2; ++ni)
#pragma unroll
      for (int r = 0; r < 4; ++r)
        Out[(size_t)(m0 + wm * 32 + mi * 16 + g * 4 + r) * 512 + n0 +
            wn * 32 + ni * 16 + ln] = acc[mi][ni][r];
}

extern "C" void kernel_launch(void* const* d_in, const int* in_sizes, int n_in,
                              void* d_out, int out_size, void* d_ws,
                              size_t ws_size, hipStream_t stream) {
  const float* x = (const float*)d_in[0];       // [2,64,48,512]
  const float* w_qkv = (const float*)d_in[1];   // [512,1536]
  const float* w_out = (const float*)d_in[2];   // [512,512]
  const float* rrow = (const float*)d_in[3];    // [127,8]
  const float* rcol = (const float*)d_in[4];    // [95,8]
  float* out = (float*)d_out;                   // [6144,512]

  unsigned short* ws16 = (unsigned short*)d_ws;
  unsigned short* xh = ws16;                    // 3145728
  unsigned short* xl = xh + 3145728;            // 3145728
  unsigned short* wqh = xl + 3145728;           // 786432
  unsigned short* wql = wqh + 786432;
  unsigned short* woh = wql + 786432;           // 262144
  unsigned short* wol = woh + 262144;
  unsigned short* Qb = wol + 262144;            // 3145728
  unsigned short* KV = Qb + 3145728;            // 16*32*12800 = 6553600
  unsigned short* Opart = KV + 6553600;         // bf16
  const size_t base_bytes =
      ((size_t)3145728 * 3 + 786432 * 2 + 262144 * 2 + 6553600) * 2;
  const size_t per_split = (size_t)3145728 * 2 + (size_t)49152 * 4;
  const int nsplit = (ws_size >= base_bytes + 2 * per_split) ? 2 : 1;
  float* Lpart = (float*)(Opart + (size_t)nsplit * 3145728);

  ga_conv_all<<<1792, 256, 0, stream>>>(x, w_qkv, w_out, xh, xl, wqh, wql, woh,
                                        wol);
  ga_mm3<128, 128><<<576, 256, 0, stream>>>(xh, xl, wqh, wql, Qb, KV);
  ga_attn16<<<24 * 16 * nsplit, 256, 0, stream>>>(
      Qb, KV, rrow, rcol, Opart, Lpart, nsplit);
  if (nsplit == 2)
    ga_outmm<2><<<768, 256, 0, stream>>>(Opart, Lpart, woh, out);
  else
    ga_outmm<1><<<768, 256, 0, stream>>>(Opart, Lpart, woh, out);
}